// Round 2
// baseline (58.314 us; speedup 1.0000x reference)
//
#include <hip/hip_runtime.h>
#include <hip/hip_bf16.h>

#define SEP_ID 102
#define BB 64
#define SS 512
#define HH 1024

// One fused kernel: per-block meta recompute -> partial accumulation ->
// split-K style last-block-per-batch finalize (fixed-order reduction,
// deterministic).  grid = (NS, B), block = 256; thread t owns float4 at h=4t.
// part layout: part[((b*NS + sc)*2 + seg)*HH + h], seg 0=title 1=lead.
__global__ __launch_bounds__(256) void fused_pool_kernel(
    const float* __restrict__ hs,
    const int*  __restrict__ ids,
    float*      __restrict__ part,
    int*        __restrict__ counters,   // [BB], zeroed per call
    float*      __restrict__ out,
    int NS, int SC)
{
    const int sc = blockIdx.x;
    const int b  = blockIdx.y;
    const int t  = threadIdx.x;

    // ---- meta (recomputed per block; ids L2-hot) ----
    __shared__ int s_first, s_last, s_cnt;
    __shared__ int s_islast;
    if (t == 0) { s_first = SS; s_last = -1; s_cnt = 0; }
    __syncthreads();
    #pragma unroll
    for (int k = 0; k < SS / 256; ++k) {
        int s = t + k * 256;
        if (ids[b * SS + s] == SEP_ID) {
            atomicMin(&s_first, s);
            atomicMax(&s_last, s);
            atomicAdd(&s_cnt, 1);
        }
    }
    __syncthreads();
    const int cnt      = s_cnt;
    const int has      = (cnt >= 1) ? 1 : 0;
    const int first    = has ? s_first : 0;
    const int lead_end = (cnt >= 2) ? s_last : SS;

    // ---- partial accumulation over this block's s-chunk ----
    float4 accT = make_float4(0.f, 0.f, 0.f, 0.f);
    float4 accL = make_float4(0.f, 0.f, 0.f, 0.f);

    int s0 = sc * SC;
    int s1 = s0 + SC; if (s1 > SS) s1 = SS;
    int lo = (s0 > 1) ? s0 : 1;
    int cap = has ? lead_end : 0;        // no reads at all when no sep
    int hi = (s1 < cap) ? s1 : cap;

    const float* rb = hs + (size_t)b * SS * HH + t * 4;
    int s = lo;
    for (; s + 4 <= hi; s += 4) {        // 4 independent 16B loads in flight
        float4 v0 = *reinterpret_cast<const float4*>(rb + (size_t)(s    ) * HH);
        float4 v1 = *reinterpret_cast<const float4*>(rb + (size_t)(s + 1) * HH);
        float4 v2 = *reinterpret_cast<const float4*>(rb + (size_t)(s + 2) * HH);
        float4 v3 = *reinterpret_cast<const float4*>(rb + (size_t)(s + 3) * HH);
        float wT0 = (s     < first) ? 1.f : 0.f, wL0 = (s     > first) ? 1.f : 0.f;
        float wT1 = (s + 1 < first) ? 1.f : 0.f, wL1 = (s + 1 > first) ? 1.f : 0.f;
        float wT2 = (s + 2 < first) ? 1.f : 0.f, wL2 = (s + 2 > first) ? 1.f : 0.f;
        float wT3 = (s + 3 < first) ? 1.f : 0.f, wL3 = (s + 3 > first) ? 1.f : 0.f;
        accT.x += v0.x*wT0 + v1.x*wT1 + v2.x*wT2 + v3.x*wT3;
        accT.y += v0.y*wT0 + v1.y*wT1 + v2.y*wT2 + v3.y*wT3;
        accT.z += v0.z*wT0 + v1.z*wT1 + v2.z*wT2 + v3.z*wT3;
        accT.w += v0.w*wT0 + v1.w*wT1 + v2.w*wT2 + v3.w*wT3;
        accL.x += v0.x*wL0 + v1.x*wL1 + v2.x*wL2 + v3.x*wL3;
        accL.y += v0.y*wL0 + v1.y*wL1 + v2.y*wL2 + v3.y*wL3;
        accL.z += v0.z*wL0 + v1.z*wL1 + v2.z*wL2 + v3.z*wL3;
        accL.w += v0.w*wL0 + v1.w*wL1 + v2.w*wL2 + v3.w*wL3;
    }
    for (; s < hi; ++s) {
        float4 v = *reinterpret_cast<const float4*>(rb + (size_t)s * HH);
        float wT = (s < first) ? 1.f : 0.f;
        float wL = (s > first) ? 1.f : 0.f;
        accT.x += v.x*wT; accT.y += v.y*wT; accT.z += v.z*wT; accT.w += v.w*wT;
        accL.x += v.x*wL; accL.y += v.y*wL; accL.z += v.z*wL; accL.w += v.w*wL;
    }

    // unconditional partial store (part is NOT pre-zeroed; zeros matter)
    size_t base = (((size_t)b * NS + sc) * 2) * HH + t * 4;
    *reinterpret_cast<float4*>(part + base)      = accT;
    *reinterpret_cast<float4*>(part + base + HH) = accL;

    // ---- split-K handoff: last block for batch b finalizes ----
    __syncthreads();                      // drains this block's stores (vmcnt)
    if (t == 0) {
        __threadfence();                  // release partials device-wide
        int old = atomicAdd(&counters[b], 1);
        s_islast = (old == NS - 1) ? 1 : 0;
    }
    __syncthreads();
    if (!s_islast) return;
    __threadfence();                      // acquire: see other blocks' partials

    float4 sT = make_float4(0.f, 0.f, 0.f, 0.f);
    float4 sL = make_float4(0.f, 0.f, 0.f, 0.f);
    for (int j = 0; j < NS; ++j) {        // fixed order -> deterministic
        size_t p = (((size_t)b * NS + j) * 2) * HH + t * 4;
        float4 a = *reinterpret_cast<const float4*>(part + p);
        float4 c = *reinterpret_cast<const float4*>(part + p + HH);
        sT.x += a.x; sT.y += a.y; sT.z += a.z; sT.w += a.w;
        sL.x += c.x; sL.y += c.y; sL.z += c.z; sL.w += c.w;
    }
    int cT = has ? (first - 1) : 0;            if (cT < 0) cT = 0;
    int cL = has ? (lead_end - first - 1) : 0; if (cL < 0) cL = 0;

    float4 oT, oL;
    if (cT > 0) { float d = (float)cT; oT = make_float4(sT.x/d, sT.y/d, sT.z/d, sT.w/d); }
    else        { oT = make_float4(0.f, 0.f, 0.f, 0.f); }
    if (cL > 0) { float d = (float)cL; oL = make_float4(sL.x/d, sL.y/d, sL.z/d, sL.w/d); }
    else        { oL = make_float4(0.f, 0.f, 0.f, 0.f); }

    *reinterpret_cast<float4*>(out + (size_t)b * HH + t * 4)                   = oT;
    *reinterpret_cast<float4*>(out + (size_t)BB * HH + (size_t)b * HH + t * 4) = oL;
}

extern "C" void kernel_launch(void* const* d_in, const int* in_sizes, int n_in,
                              void* d_out, int out_size, void* d_ws, size_t ws_size,
                              hipStream_t stream) {
    const float* hs = (const float*)d_in[0];
    const int*  ids = (const int*)d_in[1];
    float* out = (float*)d_out;

    // ws layout: [partials: B*NS*2*H floats][counters: B ints]
    int NS = 8;
    while (NS > 1 &&
           (size_t)BB * NS * 2 * HH * sizeof(float) + BB * sizeof(int) > ws_size)
        NS >>= 1;
    float* part     = (float*)d_ws;
    int*   counters = (int*)((char*)d_ws + (size_t)BB * NS * 2 * HH * sizeof(float));

    hipMemsetAsync(counters, 0, BB * sizeof(int), stream);

    int SC = (SS + NS - 1) / NS;
    dim3 grid(NS, BB);
    fused_pool_kernel<<<grid, 256, 0, stream>>>(hs, ids, part, counters, out, NS, SC);
}

// Round 3
// 21.620 us; speedup vs baseline: 2.6972x; 2.6972x over previous
//
#include <hip/hip_runtime.h>
#include <hip/hip_bf16.h>

#define SEP_ID 102
#define BB 64
#define SS 512
#define HH 1024

// Single kernel, zero inter-block communication.
// grid = (H/256 = 4, B = 64); block = 1024 threads = 16 waves.
// Block (hq, b) owns a 256-float slice of H for batch b.
// Wave w handles rows s = 1+w, 1+w+16, ... (interleaved), lane l owns
// float4 at h = hq*256 + l*4. Cross-wave reduction via LDS, then waves 0/1
// write title/lead means directly to out. No ws, no fences, no atomics
// beyond block-shared meta scan.
__global__ __launch_bounds__(1024) void seg_pool_kernel(
    const float* __restrict__ hs,
    const int*   __restrict__ ids,
    float*       __restrict__ out)
{
    const int hq   = blockIdx.x;       // 0..3
    const int b    = blockIdx.y;       // 0..63
    const int tid  = threadIdx.x;
    const int lane = tid & 63;
    const int wv   = tid >> 6;         // 0..15

    // ---- meta scan (block-shared atomics; ids row is 2 KB, L2-hot) ----
    __shared__ int s_first, s_last, s_cnt;
    if (tid == 0) { s_first = SS; s_last = -1; s_cnt = 0; }
    __syncthreads();
    if (tid < SS) {
        if (ids[b * SS + tid] == SEP_ID) {
            atomicMin(&s_first, tid);
            atomicMax(&s_last, tid);
            atomicAdd(&s_cnt, 1);
        }
    }
    __syncthreads();
    const int cnt      = s_cnt;
    const int has      = (cnt >= 1) ? 1 : 0;
    const int first    = has ? s_first : 0;
    const int lead_end = (cnt >= 2) ? s_last : SS;
    const int hi       = has ? lead_end : 0;   // rows >= hi never needed

    // ---- per-wave accumulation, interleaved s, 4 loads in flight ----
    const float* rb = hs + (size_t)b * SS * HH + hq * 256 + lane * 4;
    float4 aT = make_float4(0.f, 0.f, 0.f, 0.f);
    float4 aL = make_float4(0.f, 0.f, 0.f, 0.f);

    int s = 1 + wv;
    for (; s + 48 < hi; s += 64) {
        float4 v0 = *reinterpret_cast<const float4*>(rb + (size_t)(s     ) * HH);
        float4 v1 = *reinterpret_cast<const float4*>(rb + (size_t)(s + 16) * HH);
        float4 v2 = *reinterpret_cast<const float4*>(rb + (size_t)(s + 32) * HH);
        float4 v3 = *reinterpret_cast<const float4*>(rb + (size_t)(s + 48) * HH);
        float wT0 = (s      < first) ? 1.f : 0.f, wL0 = (s      > first) ? 1.f : 0.f;
        float wT1 = (s + 16 < first) ? 1.f : 0.f, wL1 = (s + 16 > first) ? 1.f : 0.f;
        float wT2 = (s + 32 < first) ? 1.f : 0.f, wL2 = (s + 32 > first) ? 1.f : 0.f;
        float wT3 = (s + 48 < first) ? 1.f : 0.f, wL3 = (s + 48 > first) ? 1.f : 0.f;
        aT.x += v0.x*wT0 + v1.x*wT1 + v2.x*wT2 + v3.x*wT3;
        aT.y += v0.y*wT0 + v1.y*wT1 + v2.y*wT2 + v3.y*wT3;
        aT.z += v0.z*wT0 + v1.z*wT1 + v2.z*wT2 + v3.z*wT3;
        aT.w += v0.w*wT0 + v1.w*wT1 + v2.w*wT2 + v3.w*wT3;
        aL.x += v0.x*wL0 + v1.x*wL1 + v2.x*wL2 + v3.x*wL3;
        aL.y += v0.y*wL0 + v1.y*wL1 + v2.y*wL2 + v3.y*wL3;
        aL.z += v0.z*wL0 + v1.z*wL1 + v2.z*wL2 + v3.z*wL3;
        aL.w += v0.w*wL0 + v1.w*wL1 + v2.w*wL2 + v3.w*wL3;
    }
    for (; s < hi; s += 16) {
        float4 v = *reinterpret_cast<const float4*>(rb + (size_t)s * HH);
        float wT = (s < first) ? 1.f : 0.f;
        float wL = (s > first) ? 1.f : 0.f;
        aT.x += v.x*wT; aT.y += v.y*wT; aT.z += v.z*wT; aT.w += v.w*wT;
        aL.x += v.x*wL; aL.y += v.y*wL; aL.z += v.z*wL; aL.w += v.w*wL;
    }

    // ---- cross-wave reduce via LDS (32 KB) ----
    __shared__ float4 ldsT[16][64];
    __shared__ float4 ldsL[16][64];
    ldsT[wv][lane] = aT;
    ldsL[wv][lane] = aL;
    __syncthreads();

    if (wv == 0) {
        float4 sT = make_float4(0.f, 0.f, 0.f, 0.f);
        #pragma unroll
        for (int j = 0; j < 16; ++j) {              // fixed order: deterministic
            float4 a = ldsT[j][lane];
            sT.x += a.x; sT.y += a.y; sT.z += a.z; sT.w += a.w;
        }
        int cT = has ? (first - 1) : 0; if (cT < 0) cT = 0;
        float4 o;
        if (cT > 0) { float d = (float)cT; o = make_float4(sT.x/d, sT.y/d, sT.z/d, sT.w/d); }
        else        { o = make_float4(0.f, 0.f, 0.f, 0.f); }
        *reinterpret_cast<float4*>(out + (size_t)b * HH + hq * 256 + lane * 4) = o;
    } else if (wv == 1) {
        float4 sL = make_float4(0.f, 0.f, 0.f, 0.f);
        #pragma unroll
        for (int j = 0; j < 16; ++j) {
            float4 a = ldsL[j][lane];
            sL.x += a.x; sL.y += a.y; sL.z += a.z; sL.w += a.w;
        }
        int cL = has ? (lead_end - first - 1) : 0; if (cL < 0) cL = 0;
        float4 o;
        if (cL > 0) { float d = (float)cL; o = make_float4(sL.x/d, sL.y/d, sL.z/d, sL.w/d); }
        else        { o = make_float4(0.f, 0.f, 0.f, 0.f); }
        *reinterpret_cast<float4*>(out + (size_t)BB * HH + (size_t)b * HH + hq * 256 + lane * 4) = o;
    }
}

extern "C" void kernel_launch(void* const* d_in, const int* in_sizes, int n_in,
                              void* d_out, int out_size, void* d_ws, size_t ws_size,
                              hipStream_t stream) {
    const float* hs = (const float*)d_in[0];
    const int*  ids = (const int*)d_in[1];
    float* out = (float*)d_out;

    dim3 grid(HH / 256, BB);
    seg_pool_kernel<<<grid, 1024, 0, stream>>>(hs, ids, out);
}